// Round 19
// baseline (998.965 us; speedup 1.0000x reference)
//
#include <hip/hip_runtime.h>

// images (16,3,32,32) f32, kernel (2048,3,6,6) f32, bias (2048,) f32.
// out = (d < d_(128) per position) ? 1 : 0, d = [b-c, b-cf, c+b, cf+b].
// Selection = H3 AND H4 (proven: rounds 6,7,8,10,11,12,16,17,18 absmax 0.0;
// round-13 H4-only FAILED -> both load-bearing; intersection FROZEN).
// Bit-frozen accumulator sequences (each accumulator's own op order):
//   c3 : mul+add, k=(kh,kw,ci) ascending, weight w[ci][kh][kw]
//   cf3: mul+add, k=(kh,kw,ci) ascending, weight w[ci][kh][5-kw]
//   c4 : fmaf,    k=(kw,kh,ci) ascending, weight w[ci][kh][kw]
//   cf4: fmaf,    k=(kw,kh,ci) ascending, weight w[ci][kh][5-kw]
//
// Round-19: tail REVERTED to round-17's proven split (round-18 fusion
// regressed -50us: keeping v[]/bb[] live through bisection cut occupancy in
// the scattered-load phase). Conv: 3 adjacent-ow positions/thread
// (x[3][6][8] shared window) amortizes the 108 readlanes + weight loads
// 3x (~10% fewer instructions); stores stay coalesced (3 consecutive
// float4/thread). Chain orders verbatim per accumulator.

#define NPOS 729   // 27*27
#define NTHR 11664 // 16*729
#define FCH 16     // filters per conv block

__device__ __forceinline__ unsigned map32(float x) {
    unsigned v = __float_as_uint(x);
    return (v & 0x80000000u) ? ~v : (v | 0x80000000u);
}

// ---------------- prep: pad weights to 128-dword stride (natural order) ----------------
__global__ __launch_bounds__(128) void prep_w1(
    const float* __restrict__ wgt, float* __restrict__ s1)
{
    int f = blockIdx.x;
    int t = threadIdx.x;
    s1[f * 128 + t] = (t < 108) ? wgt[f * 108 + t] : 0.f;
}

// weight fetch: compile-time pos (<108), natural layout (ci*6+kh)*6+kw
#define RLW(pos) __int_as_float(__builtin_amdgcn_readlane(                      \
    ((pos) < 64 ? wv0 : wv1), (pos) & 63))
#define WIDX(ci, kh, kw) (((ci) * 6 + (kh)) * 6 + (kw))

// ---------------- conv: 3 pos/thread, H3+H4, shared readlanes ----------------
__global__ __launch_bounds__(256) void conv_rl3p(
    const float* __restrict__ img, const float* __restrict__ s1,
    float4* __restrict__ Bp)
{
    // blockIdx.x = fg + 128*n; 128 fgroups of FCH=16 filters; block covers
    // all 729 positions of image n: t<243 -> (oh = t/9, ow0 = (t%9)*3)
    int bx = blockIdx.x;
    int fg = bx & 127;
    int n  = bx >> 7;
    int t  = threadIdx.x;
    int lane = t & 63;

    bool act = t < 243;
    int tt  = act ? t : 242;
    int oh  = tt / 9, ow0 = (tt % 9) * 3;

    float x[3][6][8];      // cols ow0..ow0+7 (ow0<=24 -> max col 31, in range)
    #pragma unroll
    for (int ci = 0; ci < 3; ci++)
        #pragma unroll
        for (int kh = 0; kh < 6; kh++)
            #pragma unroll
            for (int c = 0; c < 8; c++)
                x[ci][kh][c] = img[((n * 3 + ci) * 32 + oh + kh) * 32 + ow0 + c];

    const int* sw = (const int*)s1;
    int f0 = fg * FCH;
    int wv0 = sw[f0 * 128 + lane];
    int wv1 = sw[f0 * 128 + 64 + lane];

    #pragma unroll 1
    for (int fi = 0; fi < FCH; fi++) {
        int f = f0 + fi;
        // prefetch next filter's weight dwords (register double-buffer)
        int nf = (fi == FCH - 1) ? f : (f + 1);
        int nv0 = sw[nf * 128 + lane];
        int nv1 = sw[nf * 128 + 64 + lane];

        float c3[3]  = {0.f, 0.f, 0.f}, cf3[3] = {0.f, 0.f, 0.f};
        float c4[3]  = {0.f, 0.f, 0.f}, cf4[3] = {0.f, 0.f, 0.f};

        // H3: c3/cf3, each chain (kh,kw,ci) ascending — verbatim sequences
        #pragma unroll
        for (int kh = 0; kh < 6; kh++)
            #pragma unroll
            for (int kw = 0; kw < 6; kw++)
                #pragma unroll
                for (int ci = 0; ci < 3; ci++) {
                    float wa = RLW(WIDX(ci, kh, kw));
                    float wb = RLW(WIDX(ci, kh, 5 - kw));
                    #pragma unroll
                    for (int q = 0; q < 3; q++) {
                        float xx = x[ci][kh][kw + q];
                        c3[q]  = __fadd_rn(c3[q],  __fmul_rn(wa, xx));
                        cf3[q] = __fadd_rn(cf3[q], __fmul_rn(wb, xx));
                    }
                }

        // H4: c4/cf4, each chain (kw,kh,ci) ascending — verbatim sequences
        #pragma unroll
        for (int kw = 0; kw < 6; kw++)
            #pragma unroll
            for (int kh = 0; kh < 6; kh++)
                #pragma unroll
                for (int ci = 0; ci < 3; ci++) {
                    float wa = RLW(WIDX(ci, kh, kw));
                    float wb = RLW(WIDX(ci, kh, 5 - kw));
                    #pragma unroll
                    for (int q = 0; q < 3; q++) {
                        float xx = x[ci][kh][kw + q];
                        c4[q]  = fmaf(wa, xx, c4[q]);
                        cf4[q] = fmaf(wb, xx, cf4[q]);
                    }
                }

        if (act) {
            long base = ((long)n * 2048 + f) * NPOS + oh * 27 + ow0;
            #pragma unroll
            for (int q = 0; q < 3; q++)
                Bp[base + q] = make_float4(c3[q], cf3[q], c4[q], cf4[q]);
        }
        wv0 = nv0; wv1 = nv1;
    }
}

// ---------------- thresh: 256-thread parity-buffered dual bisection ----------------
// (round-17 proven; reads merged float4 Bp)
// Min-key pruning valid: every tested cutoff stays below key(0) (the kth
// value is deep-negative) and max(b±c) = b+|c| >= 0, so counts over the
// 4096 min-keys equal counts over all 8192 d-values (per hypothesis).
__global__ __launch_bounds__(256) void thresh_kernel(
    const float4* __restrict__ Bp, const float* __restrict__ bias,
    unsigned* __restrict__ thr)
{
    // XCD swizzle: consecutive p share an XCD L2 (11664 = 8*1458, bijective)
    int bx = blockIdx.x;
    int w  = (bx & 7) * 1458 + (bx >> 3);
    int n = w / NPOS;
    int p = w % NPOS;
    int t = threadIdx.x;
    int lane = t & 63, wid = t >> 6;

    unsigned m3[2][8], m4[2][8];
    #pragma unroll
    for (int j = 0; j < 8; j++) {
        int f = t + 256 * j;
        float4 v = Bp[((long)n * 2048 + f) * NPOS + p];
        float b = bias[f];
        m3[0][j] = min(map32(__fsub_rn(b, v.x)), map32(__fadd_rn(v.x, b)));
        m3[1][j] = min(map32(__fsub_rn(b, v.y)), map32(__fadd_rn(v.y, b)));
        m4[0][j] = min(map32(__fsub_rn(b, v.z)), map32(__fadd_rn(v.z, b)));
        m4[1][j] = min(map32(__fsub_rn(b, v.w)), map32(__fadd_rn(v.w, b)));
    }

    __shared__ int partial[2][4];   // parity-buffered -> 1 barrier/round
    unsigned P3 = 0, P4 = 0;
    #pragma unroll 1
    for (int bit = 31; bit >= 0; bit--) {
        unsigned C3 = P3 | (1u << bit);
        unsigned C4 = P4 | (1u << bit);
        int cnt = 0;                // low 16: H3 count, high 16: H4 count
        #pragma unroll
        for (int k = 0; k < 2; k++)
        #pragma unroll
        for (int j = 0; j < 8; j++) {
            cnt += (m3[k][j] < C3) ? 1 : 0;
            cnt += (m4[k][j] < C4) ? (1 << 16) : 0;
        }
        #pragma unroll
        for (int off = 32; off >= 1; off >>= 1) cnt += __shfl_xor(cnt, off, 64);
        int par = bit & 1;
        if (lane == 0) partial[par][wid] = cnt;
        __syncthreads();
        int tot = partial[par][0] + partial[par][1] + partial[par][2] + partial[par][3];
        if ((tot & 0xFFFF) <= 128) P3 = C3;   // count(u<C)<=128 => u_(128)>=C
        if ((tot >> 16)    <= 128) P4 = C4;
    }
    if (t == 0) {
        thr[n * NPOS + p]        = P3;
        thr[NTHR + n * NPOS + p] = P4;
    }
}

// ---------------- writeout: lane = position, coalesced ----------------
__global__ __launch_bounds__(256) void writeout(
    const float4* __restrict__ Bp, const float* __restrict__ bias,
    const unsigned* __restrict__ thr, float* __restrict__ out)
{
    // blockIdx.x = grp + 3*(ftile + 32*n); wave w covers p-segment grp*4+w
    int bx = blockIdx.x;
    int grp = bx % 3;
    int rest = bx / 3;
    int ftile = rest & 31;
    int n = rest >> 5;
    int t = threadIdx.x;
    int w = t >> 6, lane = t & 63;
    int p = (grp * 4 + w) * 64 + lane;
    bool act = p < NPOS;

    unsigned P3 = 0, P4 = 0;
    if (act) {
        P3 = thr[n * NPOS + p];
        P4 = thr[NTHR + n * NPOS + p];
    }
    long nb = (long)n * 8192 * NPOS;

    #pragma unroll 1
    for (int fi = 0; fi < 64; fi++) {
        int f = ftile * 64 + fi;
        float b = bias[f];
        if (act) {
            float4 v = Bp[((long)n * 2048 + f) * NPOS + p];
            int s0 = (map32(__fsub_rn(b, v.x)) < P3) && (map32(__fsub_rn(b, v.z)) < P4);
            int s1 = (map32(__fsub_rn(b, v.y)) < P3) && (map32(__fsub_rn(b, v.w)) < P4);
            int s2 = (map32(__fadd_rn(v.x, b)) < P3) && (map32(__fadd_rn(v.z, b)) < P4);
            int s3 = (map32(__fadd_rn(v.y, b)) < P3) && (map32(__fadd_rn(v.w, b)) < P4);
            out[nb + (long)(f       ) * NPOS + p] = s0 ? 1.0f : 0.0f;
            out[nb + (long)(f + 2048) * NPOS + p] = s1 ? 1.0f : 0.0f;
            out[nb + (long)(f + 4096) * NPOS + p] = s2 ? 1.0f : 0.0f;
            out[nb + (long)(f + 6144) * NPOS + p] = s3 ? 1.0f : 0.0f;
        }
    }
}

// ---------------- fallback: round-6 proven kernels (no ws) ----------------
__global__ __launch_bounds__(256) void conv_h34(
    const float* __restrict__ img, const float* __restrict__ wgt,
    float* __restrict__ out)
{
    int bx = blockIdx.x;
    int ftile = bx & 31;
    int rest  = bx >> 5;
    int oh = rest % 27;
    int n  = rest / 27;
    int t  = threadIdx.x;

    __shared__ float wl[64][109];
    __shared__ float patch[3][6][32];
    for (int idx = t; idx < 64 * 108; idx += 256) {
        int fi = idx / 108, k = idx - fi * 108;
        wl[fi][k] = wgt[(ftile * 64 + fi) * 108 + k];
    }
    for (int idx = t; idx < 576; idx += 256) {
        int w = idx & 31, rr = idx >> 5;
        int ci = rr / 6, r = rr - ci * 6;
        patch[ci][r][w] = img[((n * 3 + ci) * 32 + (oh + r)) * 32 + w];
    }
    __syncthreads();

    int fidx = t & 63;
    int g    = t >> 6;
    int ow0  = g * 7;
    int ncols = (g < 3) ? 7 : 6;
    int f = ftile * 64 + fidx;
    long nb = (long)n * 8192 * NPOS;
    long pb = (long)oh * 27;

    #pragma unroll 1
    for (int i = 0; i < ncols; i++) {
        int ow = ow0 + i;
        float c3 = 0, cf3 = 0, c4 = 0, cf4 = 0;
        #pragma unroll
        for (int kh = 0; kh < 6; kh++)
        #pragma unroll
        for (int kw = 0; kw < 6; kw++)
        #pragma unroll
        for (int ci = 0; ci < 3; ci++) {
            float x = patch[ci][kh][ow + kw];
            c3  = __fadd_rn(c3,  __fmul_rn(wl[fidx][(ci*6+kh)*6 + kw],     x));
            cf3 = __fadd_rn(cf3, __fmul_rn(wl[fidx][(ci*6+kh)*6 + 5 - kw], x));
        }
        #pragma unroll
        for (int kw = 0; kw < 6; kw++)
        #pragma unroll
        for (int kh = 0; kh < 6; kh++)
        #pragma unroll
        for (int ci = 0; ci < 3; ci++) {
            float x = patch[ci][kh][ow + kw];
            c4  = fmaf(wl[fidx][(ci*6+kh)*6 + kw],     x, c4);
            cf4 = fmaf(wl[fidx][(ci*6+kh)*6 + 5 - kw], x, cf4);
        }
        long pp = pb + ow;
        out[nb + (long)(f       ) * NPOS + pp] = c3;
        out[nb + (long)(f + 2048) * NPOS + pp] = cf3;
        out[nb + (long)(f + 4096) * NPOS + pp] = c4;
        out[nb + (long)(f + 6144) * NPOS + pp] = cf4;
    }
}

__device__ __forceinline__ unsigned bisect128(const unsigned (&u)[4][8],
                                              int lane, int wid, int* partial)
{
    unsigned P = 0;
    #pragma unroll 1
    for (int bit = 31; bit >= 0; bit--) {
        unsigned C = P | (1u << bit);
        int cnt = 0;
        #pragma unroll
        for (int q = 0; q < 4; q++)
            #pragma unroll
            for (int j = 0; j < 8; j++) cnt += (u[q][j] < C) ? 1 : 0;
        #pragma unroll
        for (int off = 32; off >= 1; off >>= 1) cnt += __shfl_xor(cnt, off, 64);
        if (lane == 0) partial[wid] = cnt;
        __syncthreads();
        int tot = partial[0] + partial[1] + partial[2] + partial[3];
        __syncthreads();
        if (tot <= 128) P = C;
    }
    return P;
}

__global__ __launch_bounds__(256) void sel_h34(
    const float* __restrict__ bias, float* out)
{
    int bx = blockIdx.x;
    int n = bx / NPOS;
    int p = bx % NPOS;
    int t = threadIdx.x;
    int lane = t & 63, wid = t >> 6;
    __shared__ int partial[4];

    unsigned u3[4][8], u4[4][8];
    long nb = (long)n * 8192 * NPOS;
    #pragma unroll
    for (int j = 0; j < 8; j++) {
        int f = t + 256 * j;
        float c3  = out[nb + (long)(f       ) * NPOS + p];
        float cf3 = out[nb + (long)(f + 2048) * NPOS + p];
        float c4  = out[nb + (long)(f + 4096) * NPOS + p];
        float cf4 = out[nb + (long)(f + 6144) * NPOS + p];
        float b   = bias[f];
        u3[0][j] = map32(__fsub_rn(b, c3));
        u3[1][j] = map32(__fsub_rn(b, cf3));
        u3[2][j] = map32(__fadd_rn(c3, b));
        u3[3][j] = map32(__fadd_rn(cf3, b));
        u4[0][j] = map32(__fsub_rn(b, c4));
        u4[1][j] = map32(__fsub_rn(b, cf4));
        u4[2][j] = map32(__fadd_rn(c4, b));
        u4[3][j] = map32(__fadd_rn(cf4, b));
    }
    unsigned P3 = bisect128(u3, lane, wid, partial);
    unsigned P4 = bisect128(u4, lane, wid, partial);
    #pragma unroll
    for (int j = 0; j < 8; j++) {
        int f = t + 256 * j;
        #pragma unroll
        for (int q = 0; q < 4; q++) {
            int s = (u3[q][j] < P3) && (u4[q][j] < P4);
            out[nb + (long)(q * 2048 + f) * NPOS + p] = s ? 1.0f : 0.0f;
        }
    }
}

extern "C" void kernel_launch(void* const* d_in, const int* in_sizes, int n_in,
                              void* d_out, int out_size, void* d_ws, size_t ws_size,
                              hipStream_t stream)
{
    const float* img  = (const float*)d_in[0];
    const float* wgt  = (const float*)d_in[1];
    const float* bias = (const float*)d_in[2];
    float* out = (float*)d_out;

    size_t bpB  = (size_t)16 * 2048 * NPOS * sizeof(float4);   // 382,205,952
    size_t thrB = (size_t)2 * NTHR * sizeof(unsigned);         //      93,312
    size_t s1B  = (size_t)2048 * 128 * sizeof(float);          //   1,048,576
    size_t need = bpB + thrB + s1B;

    if (ws_size >= need) {
        float4*   Bp  = (float4*)d_ws;
        unsigned* thr = (unsigned*)((char*)d_ws + bpB);
        float*    s1  = (float*)((char*)d_ws + bpB + thrB);
        prep_w1<<<2048, 128, 0, stream>>>(wgt, s1);
        conv_rl3p<<<128 * 16, 256, 0, stream>>>(img, s1, Bp);
        thresh_kernel<<<NTHR, 256, 0, stream>>>(Bp, bias, thr);
        writeout<<<16 * 32 * 3, 256, 0, stream>>>(Bp, bias, thr, out);
    } else {
        conv_h34<<<16 * 27 * 32, 256, 0, stream>>>(img, wgt, out);
        sel_h34<<<NTHR, 256, 0, stream>>>(bias, out);
    }
}

// Round 20
// 818.948 us; speedup vs baseline: 1.2198x; 1.2198x over previous
//
#include <hip/hip_runtime.h>

// images (16,3,32,32) f32, kernel (2048,3,6,6) f32, bias (2048,) f32.
// out = (d < d_(128) per position) ? 1 : 0, d = [b-c, b-cf, c+b, cf+b].
// Selection = H3 AND H4 (proven: rounds 6,7,8,10,11,12,16,17,18,19 all
// absmax 0.0; round-13 H4-only FAILED -> both load-bearing; FROZEN).
// Bit-frozen accumulator sequences (each accumulator's own op order):
//   c3 : mul+add, k=(kh,kw,ci) ascending, weight w[ci][kh][kw]
//   cf3: mul+add, k=(kh,kw,ci) ascending, weight w[ci][kh][5-kw]
//   c4 : fmaf,    k=(kw,kh,ci) ascending, weight w[ci][kh][kw]
//   cf4: fmaf,    k=(kw,kh,ci) ascending, weight w[ci][kh][5-kw]
//
// Round-20 = round-17 VERBATIM (best proven: 820 us).
// Closed levers (all measured, all regressed or walled):
//  - conv weight feed: LDS (~900+), s_load (817), readlane (450, VALU 79%)
//  - conv position-sharing: 3-pos tried twice (rounds 11/19) -> VGPR 256,
//    occupancy collapse, regression. Closed.
//  - tail: ballot-fusion (+50), single-wave thresh (+80) -> proven split
//    (thresh 256-thread parity + coalesced writeout) stands at ~370 us.

#define NPOS 729   // 27*27
#define NTHR 11664 // 16*729
#define FCH 16     // filters per conv block

__device__ __forceinline__ unsigned map32(float x) {
    unsigned v = __float_as_uint(x);
    return (v & 0x80000000u) ? ~v : (v | 0x80000000u);
}

// ---------------- prep: pad weights to 128-dword stride (natural order) ----------------
__global__ __launch_bounds__(128) void prep_w1(
    const float* __restrict__ wgt, float* __restrict__ s1)
{
    int f = blockIdx.x;
    int t = threadIdx.x;
    s1[f * 128 + t] = (t < 108) ? wgt[f * 108 + t] : 0.f;
}

// weight fetch: compile-time pos (<108), natural layout (ci*6+kh)*6+kw
#define RLW(pos) __int_as_float(__builtin_amdgcn_readlane(                      \
    ((pos) < 64 ? wv0 : wv1), (pos) & 63))
#define WIDX(ci, kh, kw) (((ci) * 6 + (kh)) * 6 + (kw))

// ---------------- conv: 1 pos/thread, H3+H4, shared readlanes ----------------
__global__ __launch_bounds__(256) void conv_rl34(
    const float* __restrict__ img, const float* __restrict__ s1,
    float4* __restrict__ Bp)
{
    // blockIdx.x = fg + 128*(pg + 3*n); 128 fgroups of FCH=16 filters
    int bx = blockIdx.x;
    int fg = bx & 127;
    int rest = bx >> 7;
    int pg = rest % 3;
    int n  = rest / 3;
    int t  = threadIdx.x;
    int lane = t & 63;

    bool act = t < 243;
    int p  = pg * 243 + (act ? t : 242);
    int oh = p / 27, ow = p % 27;

    float x[3][6][6];
    #pragma unroll
    for (int ci = 0; ci < 3; ci++)
        #pragma unroll
        for (int kh = 0; kh < 6; kh++)
            #pragma unroll
            for (int kw = 0; kw < 6; kw++)
                x[ci][kh][kw] = img[((n * 3 + ci) * 32 + oh + kh) * 32 + ow + kw];

    const int* sw = (const int*)s1;
    int f0 = fg * FCH;
    int wv0 = sw[f0 * 128 + lane];
    int wv1 = sw[f0 * 128 + 64 + lane];

    #pragma unroll 1
    for (int fi = 0; fi < FCH; fi++) {
        int f = f0 + fi;
        // prefetch next filter's weight dwords (register double-buffer)
        int nf = (fi == FCH - 1) ? f : (f + 1);
        int nv0 = sw[nf * 128 + lane];
        int nv1 = sw[nf * 128 + 64 + lane];

        float c3 = 0.f, cf3 = 0.f, c4 = 0.f, cf4 = 0.f;

        // H3: c3/cf3, each chain (kh,kw,ci) ascending — verbatim sequences
        #pragma unroll
        for (int kh = 0; kh < 6; kh++)
            #pragma unroll
            for (int kw = 0; kw < 6; kw++)
                #pragma unroll
                for (int ci = 0; ci < 3; ci++) {
                    float wa = RLW(WIDX(ci, kh, kw));
                    float wb = RLW(WIDX(ci, kh, 5 - kw));
                    float xx = x[ci][kh][kw];
                    c3  = __fadd_rn(c3,  __fmul_rn(wa, xx));
                    cf3 = __fadd_rn(cf3, __fmul_rn(wb, xx));
                }

        // H4: c4/cf4, each chain (kw,kh,ci) ascending — verbatim sequences
        #pragma unroll
        for (int kw = 0; kw < 6; kw++)
            #pragma unroll
            for (int kh = 0; kh < 6; kh++)
                #pragma unroll
                for (int ci = 0; ci < 3; ci++) {
                    float wa = RLW(WIDX(ci, kh, kw));
                    float wb = RLW(WIDX(ci, kh, 5 - kw));
                    float xx = x[ci][kh][kw];
                    c4  = fmaf(wa, xx, c4);
                    cf4 = fmaf(wb, xx, cf4);
                }

        if (act)
            Bp[((long)n * 2048 + f) * NPOS + p] = make_float4(c3, cf3, c4, cf4);
        wv0 = nv0; wv1 = nv1;
    }
}

// ---------------- thresh: 256-thread parity-buffered dual bisection ----------------
// Min-key pruning valid: every tested cutoff stays below key(0) (the kth
// value is deep-negative) and max(b±c) = b+|c| >= 0, so counts over the
// 4096 min-keys equal counts over all 8192 d-values (per hypothesis).
__global__ __launch_bounds__(256) void thresh_kernel(
    const float4* __restrict__ Bp, const float* __restrict__ bias,
    unsigned* __restrict__ thr)
{
    // XCD swizzle: consecutive p share an XCD L2 (11664 = 8*1458, bijective)
    int bx = blockIdx.x;
    int w  = (bx & 7) * 1458 + (bx >> 3);
    int n = w / NPOS;
    int p = w % NPOS;
    int t = threadIdx.x;
    int lane = t & 63, wid = t >> 6;

    unsigned m3[2][8], m4[2][8];
    #pragma unroll
    for (int j = 0; j < 8; j++) {
        int f = t + 256 * j;
        float4 v = Bp[((long)n * 2048 + f) * NPOS + p];
        float b = bias[f];
        m3[0][j] = min(map32(__fsub_rn(b, v.x)), map32(__fadd_rn(v.x, b)));
        m3[1][j] = min(map32(__fsub_rn(b, v.y)), map32(__fadd_rn(v.y, b)));
        m4[0][j] = min(map32(__fsub_rn(b, v.z)), map32(__fadd_rn(v.z, b)));
        m4[1][j] = min(map32(__fsub_rn(b, v.w)), map32(__fadd_rn(v.w, b)));
    }

    __shared__ int partial[2][4];   // parity-buffered -> 1 barrier/round
    unsigned P3 = 0, P4 = 0;
    #pragma unroll 1
    for (int bit = 31; bit >= 0; bit--) {
        unsigned C3 = P3 | (1u << bit);
        unsigned C4 = P4 | (1u << bit);
        int cnt = 0;                // low 16: H3 count, high 16: H4 count
        #pragma unroll
        for (int k = 0; k < 2; k++)
        #pragma unroll
        for (int j = 0; j < 8; j++) {
            cnt += (m3[k][j] < C3) ? 1 : 0;
            cnt += (m4[k][j] < C4) ? (1 << 16) : 0;
        }
        #pragma unroll
        for (int off = 32; off >= 1; off >>= 1) cnt += __shfl_xor(cnt, off, 64);
        int par = bit & 1;
        if (lane == 0) partial[par][wid] = cnt;
        __syncthreads();
        int tot = partial[par][0] + partial[par][1] + partial[par][2] + partial[par][3];
        if ((tot & 0xFFFF) <= 128) P3 = C3;   // count(u<C)<=128 => u_(128)>=C
        if ((tot >> 16)    <= 128) P4 = C4;
    }
    if (t == 0) {
        thr[n * NPOS + p]        = P3;
        thr[NTHR + n * NPOS + p] = P4;
    }
}

// ---------------- writeout: lane = position, coalesced ----------------
__global__ __launch_bounds__(256) void writeout(
    const float4* __restrict__ Bp, const float* __restrict__ bias,
    const unsigned* __restrict__ thr, float* __restrict__ out)
{
    // blockIdx.x = grp + 3*(ftile + 32*n); wave w covers p-segment grp*4+w
    int bx = blockIdx.x;
    int grp = bx % 3;
    int rest = bx / 3;
    int ftile = rest & 31;
    int n = rest >> 5;
    int t = threadIdx.x;
    int w = t >> 6, lane = t & 63;
    int p = (grp * 4 + w) * 64 + lane;
    bool act = p < NPOS;

    unsigned P3 = 0, P4 = 0;
    if (act) {
        P3 = thr[n * NPOS + p];
        P4 = thr[NTHR + n * NPOS + p];
    }
    long nb = (long)n * 8192 * NPOS;

    #pragma unroll 1
    for (int fi = 0; fi < 64; fi++) {
        int f = ftile * 64 + fi;
        float b = bias[f];
        if (act) {
            float4 v = Bp[((long)n * 2048 + f) * NPOS + p];
            int s0 = (map32(__fsub_rn(b, v.x)) < P3) && (map32(__fsub_rn(b, v.z)) < P4);
            int s1 = (map32(__fsub_rn(b, v.y)) < P3) && (map32(__fsub_rn(b, v.w)) < P4);
            int s2 = (map32(__fadd_rn(v.x, b)) < P3) && (map32(__fadd_rn(v.z, b)) < P4);
            int s3 = (map32(__fadd_rn(v.y, b)) < P3) && (map32(__fadd_rn(v.w, b)) < P4);
            out[nb + (long)(f       ) * NPOS + p] = s0 ? 1.0f : 0.0f;
            out[nb + (long)(f + 2048) * NPOS + p] = s1 ? 1.0f : 0.0f;
            out[nb + (long)(f + 4096) * NPOS + p] = s2 ? 1.0f : 0.0f;
            out[nb + (long)(f + 6144) * NPOS + p] = s3 ? 1.0f : 0.0f;
        }
    }
}

// ---------------- fallback: round-6 proven kernels (no ws) ----------------
__global__ __launch_bounds__(256) void conv_h34(
    const float* __restrict__ img, const float* __restrict__ wgt,
    float* __restrict__ out)
{
    int bx = blockIdx.x;
    int ftile = bx & 31;
    int rest  = bx >> 5;
    int oh = rest % 27;
    int n  = rest / 27;
    int t  = threadIdx.x;

    __shared__ float wl[64][109];
    __shared__ float patch[3][6][32];
    for (int idx = t; idx < 64 * 108; idx += 256) {
        int fi = idx / 108, k = idx - fi * 108;
        wl[fi][k] = wgt[(ftile * 64 + fi) * 108 + k];
    }
    for (int idx = t; idx < 576; idx += 256) {
        int w = idx & 31, rr = idx >> 5;
        int ci = rr / 6, r = rr - ci * 6;
        patch[ci][r][w] = img[((n * 3 + ci) * 32 + (oh + r)) * 32 + w];
    }
    __syncthreads();

    int fidx = t & 63;
    int g    = t >> 6;
    int ow0  = g * 7;
    int ncols = (g < 3) ? 7 : 6;
    int f = ftile * 64 + fidx;
    long nb = (long)n * 8192 * NPOS;
    long pb = (long)oh * 27;

    #pragma unroll 1
    for (int i = 0; i < ncols; i++) {
        int ow = ow0 + i;
        float c3 = 0, cf3 = 0, c4 = 0, cf4 = 0;
        #pragma unroll
        for (int kh = 0; kh < 6; kh++)
        #pragma unroll
        for (int kw = 0; kw < 6; kw++)
        #pragma unroll
        for (int ci = 0; ci < 3; ci++) {
            float x = patch[ci][kh][ow + kw];
            c3  = __fadd_rn(c3,  __fmul_rn(wl[fidx][(ci*6+kh)*6 + kw],     x));
            cf3 = __fadd_rn(cf3, __fmul_rn(wl[fidx][(ci*6+kh)*6 + 5 - kw], x));
        }
        #pragma unroll
        for (int kw = 0; kw < 6; kw++)
        #pragma unroll
        for (int kh = 0; kh < 6; kh++)
        #pragma unroll
        for (int ci = 0; ci < 3; ci++) {
            float x = patch[ci][kh][ow + kw];
            c4  = fmaf(wl[fidx][(ci*6+kh)*6 + kw],     x, c4);
            cf4 = fmaf(wl[fidx][(ci*6+kh)*6 + 5 - kw], x, cf4);
        }
        long pp = pb + ow;
        out[nb + (long)(f       ) * NPOS + pp] = c3;
        out[nb + (long)(f + 2048) * NPOS + pp] = cf3;
        out[nb + (long)(f + 4096) * NPOS + pp] = c4;
        out[nb + (long)(f + 6144) * NPOS + pp] = cf4;
    }
}

__device__ __forceinline__ unsigned bisect128(const unsigned (&u)[4][8],
                                              int lane, int wid, int* partial)
{
    unsigned P = 0;
    #pragma unroll 1
    for (int bit = 31; bit >= 0; bit--) {
        unsigned C = P | (1u << bit);
        int cnt = 0;
        #pragma unroll
        for (int q = 0; q < 4; q++)
            #pragma unroll
            for (int j = 0; j < 8; j++) cnt += (u[q][j] < C) ? 1 : 0;
        #pragma unroll
        for (int off = 32; off >= 1; off >>= 1) cnt += __shfl_xor(cnt, off, 64);
        if (lane == 0) partial[wid] = cnt;
        __syncthreads();
        int tot = partial[0] + partial[1] + partial[2] + partial[3];
        __syncthreads();
        if (tot <= 128) P = C;
    }
    return P;
}

__global__ __launch_bounds__(256) void sel_h34(
    const float* __restrict__ bias, float* out)
{
    int bx = blockIdx.x;
    int n = bx / NPOS;
    int p = bx % NPOS;
    int t = threadIdx.x;
    int lane = t & 63, wid = t >> 6;
    __shared__ int partial[4];

    unsigned u3[4][8], u4[4][8];
    long nb = (long)n * 8192 * NPOS;
    #pragma unroll
    for (int j = 0; j < 8; j++) {
        int f = t + 256 * j;
        float c3  = out[nb + (long)(f       ) * NPOS + p];
        float cf3 = out[nb + (long)(f + 2048) * NPOS + p];
        float c4  = out[nb + (long)(f + 4096) * NPOS + p];
        float cf4 = out[nb + (long)(f + 6144) * NPOS + p];
        float b   = bias[f];
        u3[0][j] = map32(__fsub_rn(b, c3));
        u3[1][j] = map32(__fsub_rn(b, cf3));
        u3[2][j] = map32(__fadd_rn(c3, b));
        u3[3][j] = map32(__fadd_rn(cf3, b));
        u4[0][j] = map32(__fsub_rn(b, c4));
        u4[1][j] = map32(__fsub_rn(b, cf4));
        u4[2][j] = map32(__fadd_rn(c4, b));
        u4[3][j] = map32(__fadd_rn(cf4, b));
    }
    unsigned P3 = bisect128(u3, lane, wid, partial);
    unsigned P4 = bisect128(u4, lane, wid, partial);
    #pragma unroll
    for (int j = 0; j < 8; j++) {
        int f = t + 256 * j;
        #pragma unroll
        for (int q = 0; q < 4; q++) {
            int s = (u3[q][j] < P3) && (u4[q][j] < P4);
            out[nb + (long)(q * 2048 + f) * NPOS + p] = s ? 1.0f : 0.0f;
        }
    }
}

extern "C" void kernel_launch(void* const* d_in, const int* in_sizes, int n_in,
                              void* d_out, int out_size, void* d_ws, size_t ws_size,
                              hipStream_t stream)
{
    const float* img  = (const float*)d_in[0];
    const float* wgt  = (const float*)d_in[1];
    const float* bias = (const float*)d_in[2];
    float* out = (float*)d_out;

    size_t bpB  = (size_t)16 * 2048 * NPOS * sizeof(float4);   // 382,205,952
    size_t thrB = (size_t)2 * NTHR * sizeof(unsigned);         //      93,312
    size_t s1B  = (size_t)2048 * 128 * sizeof(float);          //   1,048,576
    size_t need = bpB + thrB + s1B;

    if (ws_size >= need) {
        float4*   Bp  = (float4*)d_ws;
        unsigned* thr = (unsigned*)((char*)d_ws + bpB);
        float*    s1  = (float*)((char*)d_ws + bpB + thrB);
        prep_w1<<<2048, 128, 0, stream>>>(wgt, s1);
        conv_rl34<<<128 * 3 * 16, 256, 0, stream>>>(img, s1, Bp);
        thresh_kernel<<<NTHR, 256, 0, stream>>>(Bp, bias, thr);
        writeout<<<16 * 32 * 3, 256, 0, stream>>>(Bp, bias, thr, out);
    } else {
        conv_h34<<<16 * 27 * 32, 256, 0, stream>>>(img, wgt, out);
        sel_h34<<<NTHR, 256, 0, stream>>>(bias, out);
    }
}